// Round 12
// baseline (483.772 us; speedup 1.0000x reference)
//
#include <hip/hip_runtime.h>

typedef float floatx4 __attribute__((ext_vector_type(4)));
typedef short shortx8 __attribute__((ext_vector_type(8)));

struct P5 { const void* p[5]; };

__device__ __forceinline__ float bf16_to_f(unsigned short u) {
    union { unsigned int i; float f; } v;
    v.i = ((unsigned int)u) << 16;
    return v.f;
}
__device__ __forceinline__ unsigned short f_to_bf16(float f) {
    union { float f; unsigned int i; } v;
    v.f = f;
    unsigned int lsb = (v.i >> 16) & 1u;
    unsigned int r = v.i + 0x7fffu + lsb;
    return (unsigned short)(r >> 16);
}

#define E_TOT 2720000
#define N_TOT 180000
#define CAP 96        // max degree bound: worst-type mean 32, P(deg>=96) ~ 1e-20

// two-pass build: k_binA histograms edges into 704 buckets of 256 slots (w>>8)
// in LDS + ONE global atomic per (block,bucket) reservation -> global atomics
// 2.72M -> ~230K. v2: no LDS record stash (was 48KB capping the whole merged
// kernel at 2 blocks/CU); phase 2 re-reads the block's edge slice from global
// (L2-hot after phase 1). LDS now 8.4KB -> occupancy-uncapped, cast blocks too.
#define EPB 8192           // edges per k_binA block
#define NBA 333            // ceil(E_TOT / EPB)
#define NBKT2 704          // ceil(N_TOT / 256)
#define BCAP2 9216         // worst bucket (drug region): mean 8192, sigma ~90 -> +11 sigma
#define GCNT_STRIDE 16     // one counter per 64B line
#define NB_MERGED (NBA + 11024)  // 333 bin + 10000 cast + 512 bw0 + 512 bw1

// ---------------- zero (bucket counters) ----------------
__global__ __launch_bounds__(256) void k_zero(int* __restrict__ p, int n) {
    int i = blockIdx.x * 256 + threadIdx.x;
    if (i < n) p[i] = 0;
}

// ---------------- build_w body (fp32 in, bf16 out) ----------------
// Wt layouts (bf16, [128 n x K k] row-major):
//  gene K=512: [Wl(e0)|Wl(e3)|Wl(e4)|Wr(e0)+Wr(e3)+Wr(e4)]
//  drug K=256: [Wl(e1)|Wr(e1)]   dis K=256: [Wl(e2)|Wr(e2)]
__device__ void build_w_body(const float* Wl, const float* Wr, const float* bl,
                             int l, int t,
                             unsigned short* Wg, unsigned short* Wd,
                             unsigned short* Ws, float* bg, float* bd, float* bs) {
    if (t < 128 * 512) {
        int n = t >> 9;
        int kg = t & 511;
        int b = kg >> 7, k = kg & 127;
        float v;
        if (b == 0)
            v = Wl[(((size_t)l * 5 + 0) * 128 + n) * 128 + k];
        else if (b == 1)
            v = Wl[(((size_t)l * 5 + 3) * 128 + n) * 128 + k];
        else if (b == 2)
            v = Wl[(((size_t)l * 5 + 4) * 128 + n) * 128 + k];
        else
            v = Wr[(((size_t)l * 5 + 0) * 128 + n) * 128 + k] +
                Wr[(((size_t)l * 5 + 3) * 128 + n) * 128 + k] +
                Wr[(((size_t)l * 5 + 4) * 128 + n) * 128 + k];
        Wg[n * 512 + kg] = f_to_bf16(v);
    } else if (t < 131072) {
        int t2 = t - 65536;
        int which = (t2 >= 32768) ? 1 : 0;  // 0=drug(e1), 1=disease(e2)
        int t3 = which ? t2 - 32768 : t2;
        int n = t3 >> 8;
        int kg = t3 & 255;
        int b = kg >> 7, k = kg & 127;
        int ei = which ? 2 : 1;
        float v = (b == 0) ? Wl[(((size_t)l * 5 + ei) * 128 + n) * 128 + k]
                           : Wr[(((size_t)l * 5 + ei) * 128 + n) * 128 + k];
        (which ? Ws : Wd)[n * 256 + kg] = f_to_bf16(v);
    }
    if (t < 128) {
        int n = t;
        bg[n] = bl[((size_t)l * 5 + 0) * 128 + n] +
                bl[((size_t)l * 5 + 3) * 128 + n] +
                bl[((size_t)l * 5 + 4) * 128 + n];
        bd[n] = bl[((size_t)l * 5 + 1) * 128 + n];
        bs[n] = bl[((size_t)l * 5 + 2) * 128 + n];
    }
}

// ---------------- pass A: LDS-histogram binning + block reservation ----------
// blocks [0,NBA): bin 8192 edges each; [NBA,NBA+10000): cast; then 2x512 build_w.
__global__ __launch_bounds__(256) void k_binA(P5 src, P5 dst,
                                              int* __restrict__ gCnt,
                                              unsigned int* __restrict__ bktBuf,
                                              const float* __restrict__ drug,
                                              const float* __restrict__ dis,
                                              const float* __restrict__ gene,
                                              unsigned short* __restrict__ xb,
                                              const float* __restrict__ Wl,
                                              const float* __restrict__ Wr,
                                              const float* __restrict__ bl,
                                              unsigned short* __restrict__ Wg0,
                                              unsigned short* __restrict__ Wd0,
                                              unsigned short* __restrict__ Ws0,
                                              float* __restrict__ bg0,
                                              float* __restrict__ bd0,
                                              float* __restrict__ bs0,
                                              unsigned short* __restrict__ Wg1,
                                              unsigned short* __restrict__ Wd1,
                                              unsigned short* __restrict__ Ws1,
                                              float* __restrict__ bg1,
                                              float* __restrict__ bd1,
                                              float* __restrict__ bs1) {
    __shared__ int hist[NBKT2];     // 2.75 KB
    __shared__ int gbase[NBKT2];
    __shared__ int cursor[NBKT2];
    const int b = blockIdx.x;
    const int tid = threadIdx.x;
    if (b < NBA) {
        for (int t = tid; t < NBKT2; t += 256) hist[t] = 0;
        __syncthreads();
        const int ebase[5] = {0, 640000, 1280000, 1600000, 1920000};
        const int noff[5]  = {0, 50000, 70000, 80000, 130000};
        // phase 1: histogram dst buckets (dst-only reads)
        for (int r = 0; r < 32; ++r) {
            int g = b * EPB + r * 256 + tid;
            if (g < E_TOT) {
                int t = (g < 640000) ? 0 : (g < 1280000) ? 1 : (g < 1600000) ? 2
                        : (g < 1920000) ? 3 : 4;
                int e = g - ebase[t];
                int d = ((const int*)dst.p[t])[e];
                int w = noff[t] + d;
                atomicAdd(&hist[w >> 8], 1);
            }
        }
        __syncthreads();
        // one global atomic per nonempty bucket reserves a contiguous range
        for (int t = tid; t < NBKT2; t += 256) {
            int h = hist[t];
            gbase[t] = h ? atomicAdd(&gCnt[t * GCNT_STRIDE], h) : 0;
            cursor[t] = 0;
        }
        __syncthreads();
        // phase 2: re-read edges (L2-hot) and write records into reserved ranges
        for (int r = 0; r < 32; ++r) {
            int g = b * EPB + r * 256 + tid;
            if (g < E_TOT) {
                int t = (g < 640000) ? 0 : (g < 1280000) ? 1 : (g < 1600000) ? 2
                        : (g < 1920000) ? 3 : 4;
                int e = g - ebase[t];
                int s = ((const int*)src.p[t])[e];
                int d = ((const int*)dst.p[t])[e];
                int w = noff[t] + d;
                int bk = w >> 8;
                int rank = atomicAdd(&cursor[bk], 1);
                int idx = gbase[bk] + rank;
                if (idx < BCAP2)
                    bktBuf[(size_t)bk * BCAP2 + idx] =
                        ((unsigned int)(w & 255) << 16) | (unsigned int)s;  // src < 65536
            }
        }
        return;
    }
    int pb = b - NBA;
    if (pb < 10000) {
        int i = (pb * 256 + threadIdx.x) * 4;
        if (i >= 10240000) return;
        const float* sp;
        int off;
        if (i < 2560000) { sp = drug; off = i; }
        else if (i < 3840000) { sp = dis; off = i - 2560000; }
        else { sp = gene; off = i - 3840000; }
        floatx4 v = *(const floatx4*)(sp + off);
        ushort4 r;
        r.x = f_to_bf16(v[0]);
        r.y = f_to_bf16(v[1]);
        r.z = f_to_bf16(v[2]);
        r.w = f_to_bf16(v[3]);
        *(ushort4*)(xb + i) = r;
    } else if (pb < 10512) {
        build_w_body(Wl, Wr, bl, 0, (pb - 10000) * 256 + threadIdx.x,
                     Wg0, Wd0, Ws0, bg0, bd0, bs0);
    } else {
        build_w_body(Wl, Wr, bl, 1, (pb - 10512) * 256 + threadIdx.x,
                     Wg1, Wd1, Ws1, bg1, bd1, bs1);
    }
}

// ---------------- pass B: LDS-staged placement, coalesced esF write ----------
// One block per bucket of 256 consecutive slots. Reads the bucket's records,
// places into an LDS image of esF[256][CAP] via LDS cursors, then copies the
// whole region to global coalesced. cnt[w] = final cursors.
__global__ __launch_bounds__(256) void k_placeB(const int* __restrict__ gCnt,
                                                const unsigned int* __restrict__ bktBuf,
                                                int* __restrict__ cnt,
                                                unsigned short* __restrict__ esF) {
    __shared__ __align__(16) unsigned short sE[256 * CAP];  // 48 KB
    __shared__ int scnt[256];
    const int b = blockIdx.x;
    const int tid = threadIdx.x;
    scnt[tid] = 0;
    __syncthreads();
    int n = gCnt[b * GCNT_STRIDE];
    if (n > BCAP2) n = BCAP2;
    const unsigned int* bp = bktBuf + (size_t)b * BCAP2;
    for (int i = tid; i < n; i += 256) {
        unsigned int rec = bp[i];
        int local = rec >> 16;
        int pos = atomicAdd(&scnt[local], 1);
        if (pos < CAP)
            sE[local * CAP + pos] = (unsigned short)(rec & 0xffffu);
    }
    __syncthreads();
    int w0 = b * 256;
    int nslot = N_TOT - w0;
    if (nslot > 256) nslot = 256;
    // copy out: CAP*2 = 192 B/slot = 12 uint4 per slot
    int nvec = nslot * 12;
    const uint4* s4 = (const uint4*)sE;
    uint4* g4 = (uint4*)(esF + (size_t)w0 * CAP);
    for (int i = tid; i < nvec; i += 256) g4[i] = s4[i];
    if (tid < nslot) cnt[w0 + tid] = scnt[tid];
}

// ---------------- fused aggregate over all 180000 (type,dst) slots -----------
// One wave per slot w; 4 lane-groups of 16 handle neighbors j..j+3; each lane
// covers 8 columns (16B loads); combine via shfl_xor(16,32); 16-lane store.
// v2: unroll 4 -> 16 gathers in flight per wave (was 8). Counters showed
// 2.88 TB/s < 6.3 ceiling with VALU not the throughput bound: latency-throttled.
__global__ __launch_bounds__(256) void k_agg_all(P5 xs,
                                                 const int* __restrict__ cnt,
                                                 const unsigned short* __restrict__ esF,
                                                 unsigned short* __restrict__ mean) {
    int w = blockIdx.x * 4 + (threadIdx.x >> 6);
    if (w >= N_TOT) return;
    const int lane = threadIdx.x & 63;
    const int grp = lane >> 4;        // neighbor sub-index 0..3
    const int sub = lane & 15;        // 16 lanes cover one 256B row
    const int c0 = sub << 3;          // 8 cols per lane
    int t = (w < 50000) ? 0 : (w < 70000) ? 1 : (w < 80000) ? 2 : (w < 130000) ? 3 : 4;
    int n = cnt[w];
    if (n > CAP) n = CAP;
    if (n < 0) n = 0;
    const unsigned short* ep = esF + (size_t)w * CAP;
    const unsigned short* xp = (const unsigned short*)xs.p[t] + c0;
    float s0 = 0.f, s1 = 0.f, s2 = 0.f, s3 = 0.f;
    float s4 = 0.f, s5 = 0.f, s6 = 0.f, s7 = 0.f;
    int j = 0;
#pragma unroll 4
    for (; j + 4 <= n; j += 4) {
        int sA = ep[j + grp];
        uint4 p = *(const uint4*)(xp + ((size_t)sA << 7));
        s0 += bf16_to_f((unsigned short)(p.x & 0xffffu));
        s1 += bf16_to_f((unsigned short)(p.x >> 16));
        s2 += bf16_to_f((unsigned short)(p.y & 0xffffu));
        s3 += bf16_to_f((unsigned short)(p.y >> 16));
        s4 += bf16_to_f((unsigned short)(p.z & 0xffffu));
        s5 += bf16_to_f((unsigned short)(p.z >> 16));
        s6 += bf16_to_f((unsigned short)(p.w & 0xffffu));
        s7 += bf16_to_f((unsigned short)(p.w >> 16));
    }
    int rem = n - j;
    if (grp < rem) {
        int sA = ep[j + grp];
        uint4 p = *(const uint4*)(xp + ((size_t)sA << 7));
        s0 += bf16_to_f((unsigned short)(p.x & 0xffffu));
        s1 += bf16_to_f((unsigned short)(p.x >> 16));
        s2 += bf16_to_f((unsigned short)(p.y & 0xffffu));
        s3 += bf16_to_f((unsigned short)(p.y >> 16));
        s4 += bf16_to_f((unsigned short)(p.z & 0xffffu));
        s5 += bf16_to_f((unsigned short)(p.z >> 16));
        s6 += bf16_to_f((unsigned short)(p.w & 0xffffu));
        s7 += bf16_to_f((unsigned short)(p.w >> 16));
    }
    s0 += __shfl_xor(s0, 16); s1 += __shfl_xor(s1, 16);
    s2 += __shfl_xor(s2, 16); s3 += __shfl_xor(s3, 16);
    s4 += __shfl_xor(s4, 16); s5 += __shfl_xor(s5, 16);
    s6 += __shfl_xor(s6, 16); s7 += __shfl_xor(s7, 16);
    s0 += __shfl_xor(s0, 32); s1 += __shfl_xor(s1, 32);
    s2 += __shfl_xor(s2, 32); s3 += __shfl_xor(s3, 32);
    s4 += __shfl_xor(s4, 32); s5 += __shfl_xor(s5, 32);
    s6 += __shfl_xor(s6, 32); s7 += __shfl_xor(s7, 32);
    if (lane < 16) {
        float ic = 1.0f / (float)((n > 1) ? n : 1);
        uint4 o;
        o.x = (unsigned int)f_to_bf16(s0 * ic) | ((unsigned int)f_to_bf16(s1 * ic) << 16);
        o.y = (unsigned int)f_to_bf16(s2 * ic) | ((unsigned int)f_to_bf16(s3 * ic) << 16);
        o.z = (unsigned int)f_to_bf16(s4 * ic) | ((unsigned int)f_to_bf16(s5 * ic) << 16);
        o.w = (unsigned int)f_to_bf16(s6 * ic) | ((unsigned int)f_to_bf16(s7 * ic) << 16);
        *(uint4*)(mean + ((size_t)w << 7) + c0) = o;
    }
}

// ---------------- merged fused GEMM (3 jobs per layer) ----------------
// out[M,128] = relu( ( [m0|m1|m2|x] @ Wt^T + bias ) * invk )
// blocks [0,782) gene, [782,1095) drug, [1095,1252) dis.
// v2: weight chunk for each K-step (one s = 128 cols) is LDS-staged
// cooperatively (coalesced 16B global loads), MFMA B-frags come from
// ds_read_b128. Row pad 136 ushorts (272B) -> conflict-free (m136).
struct GemmJob {
    const unsigned short *m0, *m1, *m2, *x, *Wt;
    const float* bias;
    float invk;
    void* out;
    int M, nacc;
};
struct Jobs { GemmJob j[3]; };

#define BPAD 136

template <bool OUTBF>
__global__ __launch_bounds__(256) void k_gemm3(Jobs jobs) {
    __shared__ __align__(16) unsigned short sB[128 * BPAD];  // 34.8 KB
    const int b = blockIdx.x;
    int ji, bloc;
    if (b < 782) { ji = 0; bloc = b; }
    else if (b < 1095) { ji = 1; bloc = b - 782; }
    else { ji = 2; bloc = b - 1095; }
    const GemmJob& J = jobs.j[ji];
    const int K = (J.nacc + 1) << 7;
    const int tid = threadIdx.x;
    const int lane = tid & 63;
    const int wave = tid >> 6;
    const int quad = lane >> 4;
    const int l16 = lane & 15;
    const int m_base = bloc * 64 + wave * 16;
    int row = m_base + l16;
    if (row > J.M - 1) row = J.M - 1;

    // staging coords: thread t covers row t>>1, half t&1 (64 ushorts = 8x16B)
    const int srow = tid >> 1;
    const int shalf = tid & 1;
    unsigned short* sdst = sB + srow * BPAD + shalf * 64;

    floatx4 acc[8];
#pragma unroll
    for (int i = 0; i < 8; i++) acc[i] = floatx4{0.f, 0.f, 0.f, 0.f};

    for (int s = 0; s <= J.nacc; s++) {
        // ---- stage Wt[:, s*128 .. s*128+128) into LDS (32 KB, coalesced) ----
        {
            const unsigned short* wsrc =
                J.Wt + (size_t)srow * K + (s << 7) + shalf * 64;
#pragma unroll
            for (int i = 0; i < 8; i++) {
                *(shortx8*)(sdst + i * 8) = *(const shortx8*)(wsrc + i * 8);
            }
        }
        __syncthreads();
        const unsigned short* mp =
            ((s == J.nacc) ? J.x : (s == 0) ? J.m0 : (s == 1) ? J.m1 : J.m2) +
            ((size_t)row << 7);
#pragma unroll
        for (int kq = 0; kq < 4; kq++) {
            const int ko = (kq << 5) + (quad << 3);
            shortx8 afrag = *(const shortx8*)(mp + ko);
#pragma unroll
            for (int nt = 0; nt < 8; nt++) {
                shortx8 bfrag =
                    *(const shortx8*)(sB + ((nt << 4) + l16) * BPAD + ko);
                acc[nt] = __builtin_amdgcn_mfma_f32_16x16x32_bf16(afrag, bfrag, acc[nt], 0, 0, 0);
            }
        }
        __syncthreads();
    }

    // epilogue: D mapping col=lane&15, row=quad*4+reg
#pragma unroll
    for (int nt = 0; nt < 8; nt++) {
        const int col = (nt << 4) + l16;
        const float bv = J.bias[col];
#pragma unroll
        for (int r = 0; r < 4; r++) {
            const int orow = m_base + (quad << 2) + r;
            if (orow < J.M) {
                float v = fmaxf((acc[nt][r] + bv) * J.invk, 0.f);
                if (OUTBF)
                    ((unsigned short*)J.out)[((size_t)orow << 7) + col] = f_to_bf16(v);
                else
                    ((float*)J.out)[((size_t)orow << 7) + col] = v;
            }
        }
    }
}

extern "C" void kernel_launch(void* const* d_in, const int* in_sizes, int n_in,
                              void* d_out, int out_size, void* d_ws, size_t ws_size,
                              hipStream_t stream) {
    const float* emb_drug = (const float*)d_in[0];
    const float* emb_dis  = (const float*)d_in[1];
    const float* emb_gene = (const float*)d_in[2];
    const float* Wl = (const float*)d_in[3];
    const float* Wr = (const float*)d_in[4];
    const float* bl = (const float*)d_in[5];
    P5 srcs = {{d_in[6], d_in[8], d_in[10], d_in[12], d_in[14]}};
    P5 dsts = {{d_in[7], d_in[9], d_in[11], d_in[13], d_in[15]}};

    char* base = (char*)d_ws;
    size_t off = 0;
    auto alloc = [&](size_t bytes) -> void* {
        void* r = base + off;
        off = (off + bytes + 255) & ~(size_t)255;
        return r;
    };
    int* cnt = (int*)alloc((size_t)N_TOT * 4);
    unsigned short* esF = (unsigned short*)alloc((size_t)N_TOT * CAP * 2);
    unsigned short* mean = (unsigned short*)alloc(180000ull * 128 * 2);
    unsigned short* xb = (unsigned short*)alloc(80000ull * 128 * 2);
    unsigned short* xb_drug = xb;
    unsigned short* xb_dis  = xb + 20000ull * 128;
    unsigned short* xb_gene = xb + 30000ull * 128;
    unsigned short* x1_drug = (unsigned short*)alloc(20000ull * 128 * 2);
    unsigned short* x1_dis  = (unsigned short*)alloc(10000ull * 128 * 2);
    unsigned short* x1_gene = (unsigned short*)alloc(50000ull * 128 * 2);
    unsigned short* Wg0 = (unsigned short*)alloc(128ull * 512 * 2);
    unsigned short* Wd0 = (unsigned short*)alloc(128ull * 256 * 2);
    unsigned short* Ws0 = (unsigned short*)alloc(128ull * 256 * 2);
    unsigned short* Wg1 = (unsigned short*)alloc(128ull * 512 * 2);
    unsigned short* Wd1 = (unsigned short*)alloc(128ull * 256 * 2);
    unsigned short* Ws1 = (unsigned short*)alloc(128ull * 256 * 2);
    float* bg0 = (float*)alloc(128 * 4);
    float* bd0 = (float*)alloc(128 * 4);
    float* bs0 = (float*)alloc(128 * 4);
    float* bg1 = (float*)alloc(128 * 4);
    float* bd1 = (float*)alloc(128 * 4);
    float* bs1 = (float*)alloc(128 * 4);
    int* gCnt = (int*)alloc((size_t)NBKT2 * GCNT_STRIDE * 4);
    unsigned int* bktBuf = (unsigned int*)alloc((size_t)NBKT2 * BCAP2 * 4);

    // ---- zero bucket counters, bin (+cast+build_w), place into esF ----
    k_zero<<<(NBKT2 * GCNT_STRIDE + 255) / 256, 256, 0, stream>>>(
        gCnt, NBKT2 * GCNT_STRIDE);
    k_binA<<<NB_MERGED, 256, 0, stream>>>(srcs, dsts, gCnt, bktBuf,
                                          emb_drug, emb_dis, emb_gene, xb,
                                          Wl, Wr, bl,
                                          Wg0, Wd0, Ws0, bg0, bd0, bs0,
                                          Wg1, Wd1, Ws1, bg1, bd1, bs1);
    k_placeB<<<NBKT2, 256, 0, stream>>>(gCnt, bktBuf, cnt, esF);

    const long long MOFF1 = 50000ll * 128, MOFF2 = 70000ll * 128;
    const long long MOFF3 = 80000ll * 128, MOFF4 = 130000ll * 128;

    // ---- layer 1 ----
    P5 xs1 = {{xb_drug, xb_gene, xb_gene, xb_dis, xb_gene}};
    k_agg_all<<<(N_TOT + 3) / 4, 256, 0, stream>>>(xs1, cnt, esF, mean);
    Jobs jobs1 = {{
        {mean, mean + MOFF3, mean + MOFF4, xb_gene, Wg0, bg0, 1.0f / 3.0f, x1_gene, 50000, 3},
        {mean + MOFF1, nullptr, nullptr, xb_drug, Wd0, bd0, 1.0f, x1_drug, 20000, 1},
        {mean + MOFF2, nullptr, nullptr, xb_dis, Ws0, bs0, 1.0f, x1_dis, 10000, 1},
    }};
    k_gemm3<true><<<1252, 256, 0, stream>>>(jobs1);

    // ---- layer 2 ----
    P5 xs2 = {{x1_drug, x1_gene, x1_gene, x1_dis, x1_gene}};
    k_agg_all<<<(N_TOT + 3) / 4, 256, 0, stream>>>(xs2, cnt, esF, mean);
    float* outp = (float*)d_out;
    Jobs jobs2 = {{
        {mean, mean + MOFF3, mean + MOFF4, x1_gene, Wg1, bg1, 1.0f / 3.0f,
         outp + 30000ull * 128, 50000, 3},
        {mean + MOFF1, nullptr, nullptr, x1_drug, Wd1, bd1, 1.0f, outp, 20000, 1},
        {mean + MOFF2, nullptr, nullptr, x1_dis, Ws1, bs1, 1.0f,
         outp + 20000ull * 128, 10000, 1},
    }};
    k_gemm3<false><<<1252, 256, 0, stream>>>(jobs2);
}

// Round 13
// 428.190 us; speedup vs baseline: 1.1298x; 1.1298x over previous
//
#include <hip/hip_runtime.h>

typedef float floatx4 __attribute__((ext_vector_type(4)));
typedef short shortx8 __attribute__((ext_vector_type(8)));

struct P5 { const void* p[5]; };

__device__ __forceinline__ float bf16_to_f(unsigned short u) {
    union { unsigned int i; float f; } v;
    v.i = ((unsigned int)u) << 16;
    return v.f;
}
__device__ __forceinline__ unsigned short f_to_bf16(float f) {
    union { float f; unsigned int i; } v;
    v.f = f;
    unsigned int lsb = (v.i >> 16) & 1u;
    unsigned int r = v.i + 0x7fffu + lsb;
    return (unsigned short)(r >> 16);
}

#define E_TOT 2720000
#define N_TOT 180000
#define CAP 96        // max degree bound: worst-type mean 32, P(deg>=96) ~ 1e-20

// two-pass build: k_binA bins edges into 704 buckets of 256 slots (w>>8) with
// per-block LDS histograms + ONE global atomic per (block,bucket) reservation.
// v3: restore LDS record stash (single edge read; R12 showed phase-2 global
// re-read + no co-resident work = loss) and EPB 8192->2048: NBA 333->1329
// blocks. R12 counters: binA ran at 21.6% occupancy (333 blocks = 1.3/CU tail,
// 5 waves/CU, latency-bound at 4% VALU / 8% HBM). 1329 blocks ~ 5/CU x 4 waves
// = 20 waves/CU. LDS 20.4KB -> 7 blocks/CU by LDS, wave-capped anyway.
#define EPB 2048           // edges per k_binA block
#define NBA 1329           // ceil(E_TOT / EPB)
#define NBKT2 704          // ceil(N_TOT / 256)
#define BCAP2 9216         // worst bucket (drug region): mean 8192, sigma ~90 -> +11 sigma
#define GCNT_STRIDE 16     // one counter per 64B line
#define NB_MERGED (NBA + 11024)  // 1329 bin + 10000 cast + 512 bw0 + 512 bw1

// ---------------- zero (bucket counters) ----------------
__global__ __launch_bounds__(256) void k_zero(int* __restrict__ p, int n) {
    int i = blockIdx.x * 256 + threadIdx.x;
    if (i < n) p[i] = 0;
}

// ---------------- build_w body (fp32 in, bf16 out) ----------------
// Wt layouts (bf16, [128 n x K k] row-major):
//  gene K=512: [Wl(e0)|Wl(e3)|Wl(e4)|Wr(e0)+Wr(e3)+Wr(e4)]
//  drug K=256: [Wl(e1)|Wr(e1)]   dis K=256: [Wl(e2)|Wr(e2)]
__device__ void build_w_body(const float* Wl, const float* Wr, const float* bl,
                             int l, int t,
                             unsigned short* Wg, unsigned short* Wd,
                             unsigned short* Ws, float* bg, float* bd, float* bs) {
    if (t < 128 * 512) {
        int n = t >> 9;
        int kg = t & 511;
        int b = kg >> 7, k = kg & 127;
        float v;
        if (b == 0)
            v = Wl[(((size_t)l * 5 + 0) * 128 + n) * 128 + k];
        else if (b == 1)
            v = Wl[(((size_t)l * 5 + 3) * 128 + n) * 128 + k];
        else if (b == 2)
            v = Wl[(((size_t)l * 5 + 4) * 128 + n) * 128 + k];
        else
            v = Wr[(((size_t)l * 5 + 0) * 128 + n) * 128 + k] +
                Wr[(((size_t)l * 5 + 3) * 128 + n) * 128 + k] +
                Wr[(((size_t)l * 5 + 4) * 128 + n) * 128 + k];
        Wg[n * 512 + kg] = f_to_bf16(v);
    } else if (t < 131072) {
        int t2 = t - 65536;
        int which = (t2 >= 32768) ? 1 : 0;  // 0=drug(e1), 1=disease(e2)
        int t3 = which ? t2 - 32768 : t2;
        int n = t3 >> 8;
        int kg = t3 & 255;
        int b = kg >> 7, k = kg & 127;
        int ei = which ? 2 : 1;
        float v = (b == 0) ? Wl[(((size_t)l * 5 + ei) * 128 + n) * 128 + k]
                           : Wr[(((size_t)l * 5 + ei) * 128 + n) * 128 + k];
        (which ? Ws : Wd)[n * 256 + kg] = f_to_bf16(v);
    }
    if (t < 128) {
        int n = t;
        bg[n] = bl[((size_t)l * 5 + 0) * 128 + n] +
                bl[((size_t)l * 5 + 3) * 128 + n] +
                bl[((size_t)l * 5 + 4) * 128 + n];
        bd[n] = bl[((size_t)l * 5 + 1) * 128 + n];
        bs[n] = bl[((size_t)l * 5 + 2) * 128 + n];
    }
}

// ---------------- pass A: LDS-histogram binning + block reservation ----------
// blocks [0,NBA): bin 2048 edges each; [NBA,NBA+10000): cast; then 2x512 build_w.
__global__ __launch_bounds__(256) void k_binA(P5 src, P5 dst,
                                              int* __restrict__ gCnt,
                                              unsigned int* __restrict__ bktBuf,
                                              const float* __restrict__ drug,
                                              const float* __restrict__ dis,
                                              const float* __restrict__ gene,
                                              unsigned short* __restrict__ xb,
                                              const float* __restrict__ Wl,
                                              const float* __restrict__ Wr,
                                              const float* __restrict__ bl,
                                              unsigned short* __restrict__ Wg0,
                                              unsigned short* __restrict__ Wd0,
                                              unsigned short* __restrict__ Ws0,
                                              float* __restrict__ bg0,
                                              float* __restrict__ bd0,
                                              float* __restrict__ bs0,
                                              unsigned short* __restrict__ Wg1,
                                              unsigned short* __restrict__ Wd1,
                                              unsigned short* __restrict__ Ws1,
                                              float* __restrict__ bg1,
                                              float* __restrict__ bd1,
                                              float* __restrict__ bs1) {
    __shared__ unsigned int recs[EPB];      // 8 KB
    __shared__ unsigned short bkts[EPB];    // 4 KB
    __shared__ int hist[NBKT2];             // 2.75 KB
    __shared__ int gbase[NBKT2];
    __shared__ int cursor[NBKT2];
    const int b = blockIdx.x;
    const int tid = threadIdx.x;
    if (b < NBA) {
        for (int t = tid; t < NBKT2; t += 256) hist[t] = 0;
        __syncthreads();
        const int ebase[5] = {0, 640000, 1280000, 1600000, 1920000};
        const int noff[5]  = {0, 50000, 70000, 80000, 130000};
        // phase 1: read edges once, stash records + bucket ids, LDS histogram
        for (int r = 0; r < 8; ++r) {
            int il = r * 256 + tid;
            int g = b * EPB + il;
            if (g < E_TOT) {
                int t = (g < 640000) ? 0 : (g < 1280000) ? 1 : (g < 1600000) ? 2
                        : (g < 1920000) ? 3 : 4;
                int e = g - ebase[t];
                int s = ((const int*)src.p[t])[e];
                int d = ((const int*)dst.p[t])[e];
                int w = noff[t] + d;
                int bk = w >> 8;
                recs[il] = ((unsigned int)(w & 255) << 16) | (unsigned int)s;  // src < 65536
                bkts[il] = (unsigned short)bk;
                atomicAdd(&hist[bk], 1);
            }
        }
        __syncthreads();
        // one global atomic per nonempty bucket reserves a contiguous range
        for (int t = tid; t < NBKT2; t += 256) {
            int h = hist[t];
            gbase[t] = h ? atomicAdd(&gCnt[t * GCNT_STRIDE], h) : 0;
            cursor[t] = 0;
        }
        __syncthreads();
        // phase 2: write records from LDS into reserved ranges
        for (int r = 0; r < 8; ++r) {
            int il = r * 256 + tid;
            int g = b * EPB + il;
            if (g < E_TOT) {
                unsigned int rec = recs[il];
                int bk = bkts[il];
                int rank = atomicAdd(&cursor[bk], 1);
                int idx = gbase[bk] + rank;
                if (idx < BCAP2)
                    bktBuf[(size_t)bk * BCAP2 + idx] = rec;
            }
        }
        return;
    }
    int pb = b - NBA;
    if (pb < 10000) {
        int i = (pb * 256 + threadIdx.x) * 4;
        if (i >= 10240000) return;
        const float* sp;
        int off;
        if (i < 2560000) { sp = drug; off = i; }
        else if (i < 3840000) { sp = dis; off = i - 2560000; }
        else { sp = gene; off = i - 3840000; }
        floatx4 v = *(const floatx4*)(sp + off);
        ushort4 r;
        r.x = f_to_bf16(v[0]);
        r.y = f_to_bf16(v[1]);
        r.z = f_to_bf16(v[2]);
        r.w = f_to_bf16(v[3]);
        *(ushort4*)(xb + i) = r;
    } else if (pb < 10512) {
        build_w_body(Wl, Wr, bl, 0, (pb - 10000) * 256 + threadIdx.x,
                     Wg0, Wd0, Ws0, bg0, bd0, bs0);
    } else {
        build_w_body(Wl, Wr, bl, 1, (pb - 10512) * 256 + threadIdx.x,
                     Wg1, Wd1, Ws1, bg1, bd1, bs1);
    }
}

// ---------------- pass B: LDS-staged placement, coalesced esF write ----------
// One block per bucket of 256 consecutive slots. Reads the bucket's records,
// places into an LDS image of esF[256][CAP] via LDS cursors, then copies the
// whole region to global coalesced. cnt[w] = final cursors.
__global__ __launch_bounds__(256) void k_placeB(const int* __restrict__ gCnt,
                                                const unsigned int* __restrict__ bktBuf,
                                                int* __restrict__ cnt,
                                                unsigned short* __restrict__ esF) {
    __shared__ __align__(16) unsigned short sE[256 * CAP];  // 48 KB
    __shared__ int scnt[256];
    const int b = blockIdx.x;
    const int tid = threadIdx.x;
    scnt[tid] = 0;
    __syncthreads();
    int n = gCnt[b * GCNT_STRIDE];
    if (n > BCAP2) n = BCAP2;
    const unsigned int* bp = bktBuf + (size_t)b * BCAP2;
    for (int i = tid; i < n; i += 256) {
        unsigned int rec = bp[i];
        int local = rec >> 16;
        int pos = atomicAdd(&scnt[local], 1);
        if (pos < CAP)
            sE[local * CAP + pos] = (unsigned short)(rec & 0xffffu);
    }
    __syncthreads();
    int w0 = b * 256;
    int nslot = N_TOT - w0;
    if (nslot > 256) nslot = 256;
    // copy out: CAP*2 = 192 B/slot = 12 uint4 per slot
    int nvec = nslot * 12;
    const uint4* s4 = (const uint4*)sE;
    uint4* g4 = (uint4*)(esF + (size_t)w0 * CAP);
    for (int i = tid; i < nvec; i += 256) g4[i] = s4[i];
    if (tid < nslot) cnt[w0 + tid] = scnt[tid];
}

// ---------------- fused aggregate over all 180000 (type,dst) slots -----------
// One wave per slot w; 4 lane-groups of 16 handle neighbors j..j+3; each lane
// covers 8 columns (16B loads); combine via shfl_xor(16,32); 16-lane store.
// v2: unroll 4 -> 16 gathers in flight per wave (was 8); adjudicated this
// round now that binA no longer masks agg in the top-5.
__global__ __launch_bounds__(256) void k_agg_all(P5 xs,
                                                 const int* __restrict__ cnt,
                                                 const unsigned short* __restrict__ esF,
                                                 unsigned short* __restrict__ mean) {
    int w = blockIdx.x * 4 + (threadIdx.x >> 6);
    if (w >= N_TOT) return;
    const int lane = threadIdx.x & 63;
    const int grp = lane >> 4;        // neighbor sub-index 0..3
    const int sub = lane & 15;        // 16 lanes cover one 256B row
    const int c0 = sub << 3;          // 8 cols per lane
    int t = (w < 50000) ? 0 : (w < 70000) ? 1 : (w < 80000) ? 2 : (w < 130000) ? 3 : 4;
    int n = cnt[w];
    if (n > CAP) n = CAP;
    if (n < 0) n = 0;
    const unsigned short* ep = esF + (size_t)w * CAP;
    const unsigned short* xp = (const unsigned short*)xs.p[t] + c0;
    float s0 = 0.f, s1 = 0.f, s2 = 0.f, s3 = 0.f;
    float s4 = 0.f, s5 = 0.f, s6 = 0.f, s7 = 0.f;
    int j = 0;
#pragma unroll 4
    for (; j + 4 <= n; j += 4) {
        int sA = ep[j + grp];
        uint4 p = *(const uint4*)(xp + ((size_t)sA << 7));
        s0 += bf16_to_f((unsigned short)(p.x & 0xffffu));
        s1 += bf16_to_f((unsigned short)(p.x >> 16));
        s2 += bf16_to_f((unsigned short)(p.y & 0xffffu));
        s3 += bf16_to_f((unsigned short)(p.y >> 16));
        s4 += bf16_to_f((unsigned short)(p.z & 0xffffu));
        s5 += bf16_to_f((unsigned short)(p.z >> 16));
        s6 += bf16_to_f((unsigned short)(p.w & 0xffffu));
        s7 += bf16_to_f((unsigned short)(p.w >> 16));
    }
    int rem = n - j;
    if (grp < rem) {
        int sA = ep[j + grp];
        uint4 p = *(const uint4*)(xp + ((size_t)sA << 7));
        s0 += bf16_to_f((unsigned short)(p.x & 0xffffu));
        s1 += bf16_to_f((unsigned short)(p.x >> 16));
        s2 += bf16_to_f((unsigned short)(p.y & 0xffffu));
        s3 += bf16_to_f((unsigned short)(p.y >> 16));
        s4 += bf16_to_f((unsigned short)(p.z & 0xffffu));
        s5 += bf16_to_f((unsigned short)(p.z >> 16));
        s6 += bf16_to_f((unsigned short)(p.w & 0xffffu));
        s7 += bf16_to_f((unsigned short)(p.w >> 16));
    }
    s0 += __shfl_xor(s0, 16); s1 += __shfl_xor(s1, 16);
    s2 += __shfl_xor(s2, 16); s3 += __shfl_xor(s3, 16);
    s4 += __shfl_xor(s4, 16); s5 += __shfl_xor(s5, 16);
    s6 += __shfl_xor(s6, 16); s7 += __shfl_xor(s7, 16);
    s0 += __shfl_xor(s0, 32); s1 += __shfl_xor(s1, 32);
    s2 += __shfl_xor(s2, 32); s3 += __shfl_xor(s3, 32);
    s4 += __shfl_xor(s4, 32); s5 += __shfl_xor(s5, 32);
    s6 += __shfl_xor(s6, 32); s7 += __shfl_xor(s7, 32);
    if (lane < 16) {
        float ic = 1.0f / (float)((n > 1) ? n : 1);
        uint4 o;
        o.x = (unsigned int)f_to_bf16(s0 * ic) | ((unsigned int)f_to_bf16(s1 * ic) << 16);
        o.y = (unsigned int)f_to_bf16(s2 * ic) | ((unsigned int)f_to_bf16(s3 * ic) << 16);
        o.z = (unsigned int)f_to_bf16(s4 * ic) | ((unsigned int)f_to_bf16(s5 * ic) << 16);
        o.w = (unsigned int)f_to_bf16(s6 * ic) | ((unsigned int)f_to_bf16(s7 * ic) << 16);
        *(uint4*)(mean + ((size_t)w << 7) + c0) = o;
    }
}

// ---------------- merged fused GEMM (3 jobs per layer) ----------------
// out[M,128] = relu( ( [m0|m1|m2|x] @ Wt^T + bias ) * invk )
// blocks [0,782) gene, [782,1095) drug, [1095,1252) dis.
// v2: weight chunk for each K-step (one s = 128 cols) is LDS-staged
// cooperatively (coalesced 16B global loads), MFMA B-frags come from
// ds_read_b128. Row pad 136 ushorts (272B) -> conflict-free (m136).
struct GemmJob {
    const unsigned short *m0, *m1, *m2, *x, *Wt;
    const float* bias;
    float invk;
    void* out;
    int M, nacc;
};
struct Jobs { GemmJob j[3]; };

#define BPAD 136

template <bool OUTBF>
__global__ __launch_bounds__(256) void k_gemm3(Jobs jobs) {
    __shared__ __align__(16) unsigned short sB[128 * BPAD];  // 34.8 KB
    const int b = blockIdx.x;
    int ji, bloc;
    if (b < 782) { ji = 0; bloc = b; }
    else if (b < 1095) { ji = 1; bloc = b - 782; }
    else { ji = 2; bloc = b - 1095; }
    const GemmJob& J = jobs.j[ji];
    const int K = (J.nacc + 1) << 7;
    const int tid = threadIdx.x;
    const int lane = tid & 63;
    const int wave = tid >> 6;
    const int quad = lane >> 4;
    const int l16 = lane & 15;
    const int m_base = bloc * 64 + wave * 16;
    int row = m_base + l16;
    if (row > J.M - 1) row = J.M - 1;

    // staging coords: thread t covers row t>>1, half t&1 (64 ushorts = 8x16B)
    const int srow = tid >> 1;
    const int shalf = tid & 1;
    unsigned short* sdst = sB + srow * BPAD + shalf * 64;

    floatx4 acc[8];
#pragma unroll
    for (int i = 0; i < 8; i++) acc[i] = floatx4{0.f, 0.f, 0.f, 0.f};

    for (int s = 0; s <= J.nacc; s++) {
        // ---- stage Wt[:, s*128 .. s*128+128) into LDS (32 KB, coalesced) ----
        {
            const unsigned short* wsrc =
                J.Wt + (size_t)srow * K + (s << 7) + shalf * 64;
#pragma unroll
            for (int i = 0; i < 8; i++) {
                *(shortx8*)(sdst + i * 8) = *(const shortx8*)(wsrc + i * 8);
            }
        }
        __syncthreads();
        const unsigned short* mp =
            ((s == J.nacc) ? J.x : (s == 0) ? J.m0 : (s == 1) ? J.m1 : J.m2) +
            ((size_t)row << 7);
#pragma unroll
        for (int kq = 0; kq < 4; kq++) {
            const int ko = (kq << 5) + (quad << 3);
            shortx8 afrag = *(const shortx8*)(mp + ko);
#pragma unroll
            for (int nt = 0; nt < 8; nt++) {
                shortx8 bfrag =
                    *(const shortx8*)(sB + ((nt << 4) + l16) * BPAD + ko);
                acc[nt] = __builtin_amdgcn_mfma_f32_16x16x32_bf16(afrag, bfrag, acc[nt], 0, 0, 0);
            }
        }
        __syncthreads();
    }

    // epilogue: D mapping col=lane&15, row=quad*4+reg
#pragma unroll
    for (int nt = 0; nt < 8; nt++) {
        const int col = (nt << 4) + l16;
        const float bv = J.bias[col];
#pragma unroll
        for (int r = 0; r < 4; r++) {
            const int orow = m_base + (quad << 2) + r;
            if (orow < J.M) {
                float v = fmaxf((acc[nt][r] + bv) * J.invk, 0.f);
                if (OUTBF)
                    ((unsigned short*)J.out)[((size_t)orow << 7) + col] = f_to_bf16(v);
                else
                    ((float*)J.out)[((size_t)orow << 7) + col] = v;
            }
        }
    }
}

extern "C" void kernel_launch(void* const* d_in, const int* in_sizes, int n_in,
                              void* d_out, int out_size, void* d_ws, size_t ws_size,
                              hipStream_t stream) {
    const float* emb_drug = (const float*)d_in[0];
    const float* emb_dis  = (const float*)d_in[1];
    const float* emb_gene = (const float*)d_in[2];
    const float* Wl = (const float*)d_in[3];
    const float* Wr = (const float*)d_in[4];
    const float* bl = (const float*)d_in[5];
    P5 srcs = {{d_in[6], d_in[8], d_in[10], d_in[12], d_in[14]}};
    P5 dsts = {{d_in[7], d_in[9], d_in[11], d_in[13], d_in[15]}};

    char* base = (char*)d_ws;
    size_t off = 0;
    auto alloc = [&](size_t bytes) -> void* {
        void* r = base + off;
        off = (off + bytes + 255) & ~(size_t)255;
        return r;
    };
    int* cnt = (int*)alloc((size_t)N_TOT * 4);
    unsigned short* esF = (unsigned short*)alloc((size_t)N_TOT * CAP * 2);
    unsigned short* mean = (unsigned short*)alloc(180000ull * 128 * 2);
    unsigned short* xb = (unsigned short*)alloc(80000ull * 128 * 2);
    unsigned short* xb_drug = xb;
    unsigned short* xb_dis  = xb + 20000ull * 128;
    unsigned short* xb_gene = xb + 30000ull * 128;
    unsigned short* x1_drug = (unsigned short*)alloc(20000ull * 128 * 2);
    unsigned short* x1_dis  = (unsigned short*)alloc(10000ull * 128 * 2);
    unsigned short* x1_gene = (unsigned short*)alloc(50000ull * 128 * 2);
    unsigned short* Wg0 = (unsigned short*)alloc(128ull * 512 * 2);
    unsigned short* Wd0 = (unsigned short*)alloc(128ull * 256 * 2);
    unsigned short* Ws0 = (unsigned short*)alloc(128ull * 256 * 2);
    unsigned short* Wg1 = (unsigned short*)alloc(128ull * 512 * 2);
    unsigned short* Wd1 = (unsigned short*)alloc(128ull * 256 * 2);
    unsigned short* Ws1 = (unsigned short*)alloc(128ull * 256 * 2);
    float* bg0 = (float*)alloc(128 * 4);
    float* bd0 = (float*)alloc(128 * 4);
    float* bs0 = (float*)alloc(128 * 4);
    float* bg1 = (float*)alloc(128 * 4);
    float* bd1 = (float*)alloc(128 * 4);
    float* bs1 = (float*)alloc(128 * 4);
    int* gCnt = (int*)alloc((size_t)NBKT2 * GCNT_STRIDE * 4);
    unsigned int* bktBuf = (unsigned int*)alloc((size_t)NBKT2 * BCAP2 * 4);

    // ---- zero bucket counters, bin (+cast+build_w), place into esF ----
    k_zero<<<(NBKT2 * GCNT_STRIDE + 255) / 256, 256, 0, stream>>>(
        gCnt, NBKT2 * GCNT_STRIDE);
    k_binA<<<NB_MERGED, 256, 0, stream>>>(srcs, dsts, gCnt, bktBuf,
                                          emb_drug, emb_dis, emb_gene, xb,
                                          Wl, Wr, bl,
                                          Wg0, Wd0, Ws0, bg0, bd0, bs0,
                                          Wg1, Wd1, Ws1, bg1, bd1, bs1);
    k_placeB<<<NBKT2, 256, 0, stream>>>(gCnt, bktBuf, cnt, esF);

    const long long MOFF1 = 50000ll * 128, MOFF2 = 70000ll * 128;
    const long long MOFF3 = 80000ll * 128, MOFF4 = 130000ll * 128;

    // ---- layer 1 ----
    P5 xs1 = {{xb_drug, xb_gene, xb_gene, xb_dis, xb_gene}};
    k_agg_all<<<(N_TOT + 3) / 4, 256, 0, stream>>>(xs1, cnt, esF, mean);
    Jobs jobs1 = {{
        {mean, mean + MOFF3, mean + MOFF4, xb_gene, Wg0, bg0, 1.0f / 3.0f, x1_gene, 50000, 3},
        {mean + MOFF1, nullptr, nullptr, xb_drug, Wd0, bd0, 1.0f, x1_drug, 20000, 1},
        {mean + MOFF2, nullptr, nullptr, xb_dis, Ws0, bs0, 1.0f, x1_dis, 10000, 1},
    }};
    k_gemm3<true><<<1252, 256, 0, stream>>>(jobs1);

    // ---- layer 2 ----
    P5 xs2 = {{x1_drug, x1_gene, x1_gene, x1_dis, x1_gene}};
    k_agg_all<<<(N_TOT + 3) / 4, 256, 0, stream>>>(xs2, cnt, esF, mean);
    float* outp = (float*)d_out;
    Jobs jobs2 = {{
        {mean, mean + MOFF3, mean + MOFF4, x1_gene, Wg1, bg1, 1.0f / 3.0f,
         outp + 30000ull * 128, 50000, 3},
        {mean + MOFF1, nullptr, nullptr, x1_drug, Wd1, bd1, 1.0f, outp, 20000, 1},
        {mean + MOFF2, nullptr, nullptr, x1_dis, Ws1, bs1, 1.0f,
         outp + 20000ull * 128, 10000, 1},
    }};
    k_gemm3<false><<<1252, 256, 0, stream>>>(jobs2);
}

// Round 14
// 418.557 us; speedup vs baseline: 1.1558x; 1.0230x over previous
//
#include <hip/hip_runtime.h>

typedef float floatx4 __attribute__((ext_vector_type(4)));
typedef short shortx8 __attribute__((ext_vector_type(8)));

struct P5 { const void* p[5]; };

__device__ __forceinline__ float bf16_to_f(unsigned short u) {
    union { unsigned int i; float f; } v;
    v.i = ((unsigned int)u) << 16;
    return v.f;
}
__device__ __forceinline__ unsigned short f_to_bf16(float f) {
    union { float f; unsigned int i; } v;
    v.f = f;
    unsigned int lsb = (v.i >> 16) & 1u;
    unsigned int r = v.i + 0x7fffu + lsb;
    return (unsigned short)(r >> 16);
}

#define E_TOT 2720000
#define N_TOT 180000
#define CAP 96        // max degree bound: worst-type mean 32, P(deg>=96) ~ 1e-20

// two-pass build: k_binA bins edges into 704 buckets of 256 slots (w>>8) with
// per-block LDS histograms + ONE global atomic per (block,bucket) reservation.
// v3 (R13-verified): LDS record stash + EPB 2048 -> 1329 bin blocks; binA
// dropped out of top-5 (<95us, was 104 at EPB 8192 / 21.6% occupancy).
#define EPB 2048           // edges per k_binA block
#define NBA 1329           // ceil(E_TOT / EPB)
#define NBKT2 704          // ceil(N_TOT / 256)
#define BCAP2 9216         // worst bucket (drug region): mean 8192, sigma ~90 -> +11 sigma
#define GCNT_STRIDE 16     // one counter per 64B line
#define NB_MERGED (NBA + 11024)  // 1329 bin + 10000 cast + 512 bw0 + 512 bw1

// ---------------- zero (bucket counters) ----------------
__global__ __launch_bounds__(256) void k_zero(int* __restrict__ p, int n) {
    int i = blockIdx.x * 256 + threadIdx.x;
    if (i < n) p[i] = 0;
}

// ---------------- build_w body (fp32 in, bf16 out) ----------------
// Wt layouts (bf16, [128 n x K k] row-major):
//  gene K=512: [Wl(e0)|Wl(e3)|Wl(e4)|Wr(e0)+Wr(e3)+Wr(e4)]
//  drug K=256: [Wl(e1)|Wr(e1)]   dis K=256: [Wl(e2)|Wr(e2)]
__device__ void build_w_body(const float* Wl, const float* Wr, const float* bl,
                             int l, int t,
                             unsigned short* Wg, unsigned short* Wd,
                             unsigned short* Ws, float* bg, float* bd, float* bs) {
    if (t < 128 * 512) {
        int n = t >> 9;
        int kg = t & 511;
        int b = kg >> 7, k = kg & 127;
        float v;
        if (b == 0)
            v = Wl[(((size_t)l * 5 + 0) * 128 + n) * 128 + k];
        else if (b == 1)
            v = Wl[(((size_t)l * 5 + 3) * 128 + n) * 128 + k];
        else if (b == 2)
            v = Wl[(((size_t)l * 5 + 4) * 128 + n) * 128 + k];
        else
            v = Wr[(((size_t)l * 5 + 0) * 128 + n) * 128 + k] +
                Wr[(((size_t)l * 5 + 3) * 128 + n) * 128 + k] +
                Wr[(((size_t)l * 5 + 4) * 128 + n) * 128 + k];
        Wg[n * 512 + kg] = f_to_bf16(v);
    } else if (t < 131072) {
        int t2 = t - 65536;
        int which = (t2 >= 32768) ? 1 : 0;  // 0=drug(e1), 1=disease(e2)
        int t3 = which ? t2 - 32768 : t2;
        int n = t3 >> 8;
        int kg = t3 & 255;
        int b = kg >> 7, k = kg & 127;
        int ei = which ? 2 : 1;
        float v = (b == 0) ? Wl[(((size_t)l * 5 + ei) * 128 + n) * 128 + k]
                           : Wr[(((size_t)l * 5 + ei) * 128 + n) * 128 + k];
        (which ? Ws : Wd)[n * 256 + kg] = f_to_bf16(v);
    }
    if (t < 128) {
        int n = t;
        bg[n] = bl[((size_t)l * 5 + 0) * 128 + n] +
                bl[((size_t)l * 5 + 3) * 128 + n] +
                bl[((size_t)l * 5 + 4) * 128 + n];
        bd[n] = bl[((size_t)l * 5 + 1) * 128 + n];
        bs[n] = bl[((size_t)l * 5 + 2) * 128 + n];
    }
}

// ---------------- pass A: LDS-histogram binning + block reservation ----------
// blocks [0,NBA): bin 2048 edges each; [NBA,NBA+10000): cast; then 2x512 build_w.
__global__ __launch_bounds__(256) void k_binA(P5 src, P5 dst,
                                              int* __restrict__ gCnt,
                                              unsigned int* __restrict__ bktBuf,
                                              const float* __restrict__ drug,
                                              const float* __restrict__ dis,
                                              const float* __restrict__ gene,
                                              unsigned short* __restrict__ xb,
                                              const float* __restrict__ Wl,
                                              const float* __restrict__ Wr,
                                              const float* __restrict__ bl,
                                              unsigned short* __restrict__ Wg0,
                                              unsigned short* __restrict__ Wd0,
                                              unsigned short* __restrict__ Ws0,
                                              float* __restrict__ bg0,
                                              float* __restrict__ bd0,
                                              float* __restrict__ bs0,
                                              unsigned short* __restrict__ Wg1,
                                              unsigned short* __restrict__ Wd1,
                                              unsigned short* __restrict__ Ws1,
                                              float* __restrict__ bg1,
                                              float* __restrict__ bd1,
                                              float* __restrict__ bs1) {
    __shared__ unsigned int recs[EPB];      // 8 KB
    __shared__ unsigned short bkts[EPB];    // 4 KB
    __shared__ int hist[NBKT2];             // 2.75 KB
    __shared__ int gbase[NBKT2];
    __shared__ int cursor[NBKT2];
    const int b = blockIdx.x;
    const int tid = threadIdx.x;
    if (b < NBA) {
        for (int t = tid; t < NBKT2; t += 256) hist[t] = 0;
        __syncthreads();
        const int ebase[5] = {0, 640000, 1280000, 1600000, 1920000};
        const int noff[5]  = {0, 50000, 70000, 80000, 130000};
        // phase 1: read edges once, stash records + bucket ids, LDS histogram
        for (int r = 0; r < 8; ++r) {
            int il = r * 256 + tid;
            int g = b * EPB + il;
            if (g < E_TOT) {
                int t = (g < 640000) ? 0 : (g < 1280000) ? 1 : (g < 1600000) ? 2
                        : (g < 1920000) ? 3 : 4;
                int e = g - ebase[t];
                int s = ((const int*)src.p[t])[e];
                int d = ((const int*)dst.p[t])[e];
                int w = noff[t] + d;
                int bk = w >> 8;
                recs[il] = ((unsigned int)(w & 255) << 16) | (unsigned int)s;  // src < 65536
                bkts[il] = (unsigned short)bk;
                atomicAdd(&hist[bk], 1);
            }
        }
        __syncthreads();
        // one global atomic per nonempty bucket reserves a contiguous range
        for (int t = tid; t < NBKT2; t += 256) {
            int h = hist[t];
            gbase[t] = h ? atomicAdd(&gCnt[t * GCNT_STRIDE], h) : 0;
            cursor[t] = 0;
        }
        __syncthreads();
        // phase 2: write records from LDS into reserved ranges
        for (int r = 0; r < 8; ++r) {
            int il = r * 256 + tid;
            int g = b * EPB + il;
            if (g < E_TOT) {
                unsigned int rec = recs[il];
                int bk = bkts[il];
                int rank = atomicAdd(&cursor[bk], 1);
                int idx = gbase[bk] + rank;
                if (idx < BCAP2)
                    bktBuf[(size_t)bk * BCAP2 + idx] = rec;
            }
        }
        return;
    }
    int pb = b - NBA;
    if (pb < 10000) {
        int i = (pb * 256 + threadIdx.x) * 4;
        if (i >= 10240000) return;
        const float* sp;
        int off;
        if (i < 2560000) { sp = drug; off = i; }
        else if (i < 3840000) { sp = dis; off = i - 2560000; }
        else { sp = gene; off = i - 3840000; }
        floatx4 v = *(const floatx4*)(sp + off);
        ushort4 r;
        r.x = f_to_bf16(v[0]);
        r.y = f_to_bf16(v[1]);
        r.z = f_to_bf16(v[2]);
        r.w = f_to_bf16(v[3]);
        *(ushort4*)(xb + i) = r;
    } else if (pb < 10512) {
        build_w_body(Wl, Wr, bl, 0, (pb - 10000) * 256 + threadIdx.x,
                     Wg0, Wd0, Ws0, bg0, bd0, bs0);
    } else {
        build_w_body(Wl, Wr, bl, 1, (pb - 10512) * 256 + threadIdx.x,
                     Wg1, Wd1, Ws1, bg1, bd1, bs1);
    }
}

// ---------------- pass B: LDS-staged placement, coalesced esF write ----------
// One block per bucket of 256 consecutive slots. Reads the bucket's records,
// places into an LDS image of esF[256][CAP] via LDS cursors, then copies the
// whole region to global coalesced. cnt[w] = final cursors.
__global__ __launch_bounds__(256) void k_placeB(const int* __restrict__ gCnt,
                                                const unsigned int* __restrict__ bktBuf,
                                                int* __restrict__ cnt,
                                                unsigned short* __restrict__ esF) {
    __shared__ __align__(16) unsigned short sE[256 * CAP];  // 48 KB
    __shared__ int scnt[256];
    const int b = blockIdx.x;
    const int tid = threadIdx.x;
    scnt[tid] = 0;
    __syncthreads();
    int n = gCnt[b * GCNT_STRIDE];
    if (n > BCAP2) n = BCAP2;
    const unsigned int* bp = bktBuf + (size_t)b * BCAP2;
    for (int i = tid; i < n; i += 256) {
        unsigned int rec = bp[i];
        int local = rec >> 16;
        int pos = atomicAdd(&scnt[local], 1);
        if (pos < CAP)
            sE[local * CAP + pos] = (unsigned short)(rec & 0xffffu);
    }
    __syncthreads();
    int w0 = b * 256;
    int nslot = N_TOT - w0;
    if (nslot > 256) nslot = 256;
    // copy out: CAP*2 = 192 B/slot = 12 uint4 per slot
    int nvec = nslot * 12;
    const uint4* s4 = (const uint4*)sE;
    uint4* g4 = (uint4*)(esF + (size_t)w0 * CAP);
    for (int i = tid; i < nvec; i += 256) g4[i] = s4[i];
    if (tid < nslot) cnt[w0 + tid] = scnt[tid];
}

// ---------------- fused aggregate over all 180000 (type,dst) slots -----------
// One wave per slot w; 4 lane-groups of 16 handle neighbors j..j+3; each lane
// covers 8 columns (16B loads); combine via shfl_xor(16,32); 16-lane store.
// v3: neighbor list preloaded into LDS (192B/slot, 12 lanes x 16B). R13 showed
// unroll-4 alone was null with VGPR only 24 -> the index load (global 2B from
// esF) serialized against each gather (two-level dependent global chain).
// LDS-resident indices let gathers issue back-to-back; unroll 4 now pipelines.
// Grid is exactly N_TOT/4 blocks (180000%4==0) so __syncthreads is uniform.
__global__ __launch_bounds__(256) void k_agg_all(P5 xs,
                                                 const int* __restrict__ cnt,
                                                 const unsigned short* __restrict__ esF,
                                                 unsigned short* __restrict__ mean) {
    __shared__ __align__(16) unsigned short nb[4][CAP];  // 768 B
    const int wslot = threadIdx.x >> 6;
    int w = blockIdx.x * 4 + wslot;
    const int lane = threadIdx.x & 63;
    const int grp = lane >> 4;        // neighbor sub-index 0..3
    const int sub = lane & 15;        // 16 lanes cover one 256B row
    const int c0 = sub << 3;          // 8 cols per lane
    int t = (w < 50000) ? 0 : (w < 70000) ? 1 : (w < 80000) ? 2 : (w < 130000) ? 3 : 4;
    int n = cnt[w];
    if (n > CAP) n = CAP;
    if (n < 0) n = 0;
    const unsigned short* ep = esF + (size_t)w * CAP;
    // preload neighbor list into LDS: 12 lanes x 8 ushorts = 96 entries
    if (lane < 12)
        *(shortx8*)(&nb[wslot][lane << 3]) = *(const shortx8*)(ep + (lane << 3));
    __syncthreads();
    const unsigned short* xp = (const unsigned short*)xs.p[t] + c0;
    const unsigned short* nbp = nb[wslot];
    float s0 = 0.f, s1 = 0.f, s2 = 0.f, s3 = 0.f;
    float s4 = 0.f, s5 = 0.f, s6 = 0.f, s7 = 0.f;
    int j = 0;
#pragma unroll 4
    for (; j + 4 <= n; j += 4) {
        int sA = nbp[j + grp];
        uint4 p = *(const uint4*)(xp + ((size_t)sA << 7));
        s0 += bf16_to_f((unsigned short)(p.x & 0xffffu));
        s1 += bf16_to_f((unsigned short)(p.x >> 16));
        s2 += bf16_to_f((unsigned short)(p.y & 0xffffu));
        s3 += bf16_to_f((unsigned short)(p.y >> 16));
        s4 += bf16_to_f((unsigned short)(p.z & 0xffffu));
        s5 += bf16_to_f((unsigned short)(p.z >> 16));
        s6 += bf16_to_f((unsigned short)(p.w & 0xffffu));
        s7 += bf16_to_f((unsigned short)(p.w >> 16));
    }
    int rem = n - j;
    if (grp < rem) {
        int sA = nbp[j + grp];
        uint4 p = *(const uint4*)(xp + ((size_t)sA << 7));
        s0 += bf16_to_f((unsigned short)(p.x & 0xffffu));
        s1 += bf16_to_f((unsigned short)(p.x >> 16));
        s2 += bf16_to_f((unsigned short)(p.y & 0xffffu));
        s3 += bf16_to_f((unsigned short)(p.y >> 16));
        s4 += bf16_to_f((unsigned short)(p.z & 0xffffu));
        s5 += bf16_to_f((unsigned short)(p.z >> 16));
        s6 += bf16_to_f((unsigned short)(p.w & 0xffffu));
        s7 += bf16_to_f((unsigned short)(p.w >> 16));
    }
    s0 += __shfl_xor(s0, 16); s1 += __shfl_xor(s1, 16);
    s2 += __shfl_xor(s2, 16); s3 += __shfl_xor(s3, 16);
    s4 += __shfl_xor(s4, 16); s5 += __shfl_xor(s5, 16);
    s6 += __shfl_xor(s6, 16); s7 += __shfl_xor(s7, 16);
    s0 += __shfl_xor(s0, 32); s1 += __shfl_xor(s1, 32);
    s2 += __shfl_xor(s2, 32); s3 += __shfl_xor(s3, 32);
    s4 += __shfl_xor(s4, 32); s5 += __shfl_xor(s5, 32);
    s6 += __shfl_xor(s6, 32); s7 += __shfl_xor(s7, 32);
    if (lane < 16) {
        float ic = 1.0f / (float)((n > 1) ? n : 1);
        uint4 o;
        o.x = (unsigned int)f_to_bf16(s0 * ic) | ((unsigned int)f_to_bf16(s1 * ic) << 16);
        o.y = (unsigned int)f_to_bf16(s2 * ic) | ((unsigned int)f_to_bf16(s3 * ic) << 16);
        o.z = (unsigned int)f_to_bf16(s4 * ic) | ((unsigned int)f_to_bf16(s5 * ic) << 16);
        o.w = (unsigned int)f_to_bf16(s6 * ic) | ((unsigned int)f_to_bf16(s7 * ic) << 16);
        *(uint4*)(mean + ((size_t)w << 7) + c0) = o;
    }
}

// ---------------- merged fused GEMM (3 jobs per layer) ----------------
// out[M,128] = relu( ( [m0|m1|m2|x] @ Wt^T + bias ) * invk )
// blocks [0,782) gene, [782,1095) drug, [1095,1252) dis.
// v2: weight chunk for each K-step (one s = 128 cols) is LDS-staged
// cooperatively (coalesced 16B global loads), MFMA B-frags come from
// ds_read_b128. Row pad 136 ushorts (272B) -> conflict-free (m136).
struct GemmJob {
    const unsigned short *m0, *m1, *m2, *x, *Wt;
    const float* bias;
    float invk;
    void* out;
    int M, nacc;
};
struct Jobs { GemmJob j[3]; };

#define BPAD 136

template <bool OUTBF>
__global__ __launch_bounds__(256) void k_gemm3(Jobs jobs) {
    __shared__ __align__(16) unsigned short sB[128 * BPAD];  // 34.8 KB
    const int b = blockIdx.x;
    int ji, bloc;
    if (b < 782) { ji = 0; bloc = b; }
    else if (b < 1095) { ji = 1; bloc = b - 782; }
    else { ji = 2; bloc = b - 1095; }
    const GemmJob& J = jobs.j[ji];
    const int K = (J.nacc + 1) << 7;
    const int tid = threadIdx.x;
    const int lane = tid & 63;
    const int wave = tid >> 6;
    const int quad = lane >> 4;
    const int l16 = lane & 15;
    const int m_base = bloc * 64 + wave * 16;
    int row = m_base + l16;
    if (row > J.M - 1) row = J.M - 1;

    // staging coords: thread t covers row t>>1, half t&1 (64 ushorts = 8x16B)
    const int srow = tid >> 1;
    const int shalf = tid & 1;
    unsigned short* sdst = sB + srow * BPAD + shalf * 64;

    floatx4 acc[8];
#pragma unroll
    for (int i = 0; i < 8; i++) acc[i] = floatx4{0.f, 0.f, 0.f, 0.f};

    for (int s = 0; s <= J.nacc; s++) {
        // ---- stage Wt[:, s*128 .. s*128+128) into LDS (32 KB, coalesced) ----
        {
            const unsigned short* wsrc =
                J.Wt + (size_t)srow * K + (s << 7) + shalf * 64;
#pragma unroll
            for (int i = 0; i < 8; i++) {
                *(shortx8*)(sdst + i * 8) = *(const shortx8*)(wsrc + i * 8);
            }
        }
        __syncthreads();
        const unsigned short* mp =
            ((s == J.nacc) ? J.x : (s == 0) ? J.m0 : (s == 1) ? J.m1 : J.m2) +
            ((size_t)row << 7);
#pragma unroll
        for (int kq = 0; kq < 4; kq++) {
            const int ko = (kq << 5) + (quad << 3);
            shortx8 afrag = *(const shortx8*)(mp + ko);
#pragma unroll
            for (int nt = 0; nt < 8; nt++) {
                shortx8 bfrag =
                    *(const shortx8*)(sB + ((nt << 4) + l16) * BPAD + ko);
                acc[nt] = __builtin_amdgcn_mfma_f32_16x16x32_bf16(afrag, bfrag, acc[nt], 0, 0, 0);
            }
        }
        __syncthreads();
    }

    // epilogue: D mapping col=lane&15, row=quad*4+reg
#pragma unroll
    for (int nt = 0; nt < 8; nt++) {
        const int col = (nt << 4) + l16;
        const float bv = J.bias[col];
#pragma unroll
        for (int r = 0; r < 4; r++) {
            const int orow = m_base + (quad << 2) + r;
            if (orow < J.M) {
                float v = fmaxf((acc[nt][r] + bv) * J.invk, 0.f);
                if (OUTBF)
                    ((unsigned short*)J.out)[((size_t)orow << 7) + col] = f_to_bf16(v);
                else
                    ((float*)J.out)[((size_t)orow << 7) + col] = v;
            }
        }
    }
}

extern "C" void kernel_launch(void* const* d_in, const int* in_sizes, int n_in,
                              void* d_out, int out_size, void* d_ws, size_t ws_size,
                              hipStream_t stream) {
    const float* emb_drug = (const float*)d_in[0];
    const float* emb_dis  = (const float*)d_in[1];
    const float* emb_gene = (const float*)d_in[2];
    const float* Wl = (const float*)d_in[3];
    const float* Wr = (const float*)d_in[4];
    const float* bl = (const float*)d_in[5];
    P5 srcs = {{d_in[6], d_in[8], d_in[10], d_in[12], d_in[14]}};
    P5 dsts = {{d_in[7], d_in[9], d_in[11], d_in[13], d_in[15]}};

    char* base = (char*)d_ws;
    size_t off = 0;
    auto alloc = [&](size_t bytes) -> void* {
        void* r = base + off;
        off = (off + bytes + 255) & ~(size_t)255;
        return r;
    };
    int* cnt = (int*)alloc((size_t)N_TOT * 4);
    unsigned short* esF = (unsigned short*)alloc((size_t)N_TOT * CAP * 2);
    unsigned short* mean = (unsigned short*)alloc(180000ull * 128 * 2);
    unsigned short* xb = (unsigned short*)alloc(80000ull * 128 * 2);
    unsigned short* xb_drug = xb;
    unsigned short* xb_dis  = xb + 20000ull * 128;
    unsigned short* xb_gene = xb + 30000ull * 128;
    unsigned short* x1_drug = (unsigned short*)alloc(20000ull * 128 * 2);
    unsigned short* x1_dis  = (unsigned short*)alloc(10000ull * 128 * 2);
    unsigned short* x1_gene = (unsigned short*)alloc(50000ull * 128 * 2);
    unsigned short* Wg0 = (unsigned short*)alloc(128ull * 512 * 2);
    unsigned short* Wd0 = (unsigned short*)alloc(128ull * 256 * 2);
    unsigned short* Ws0 = (unsigned short*)alloc(128ull * 256 * 2);
    unsigned short* Wg1 = (unsigned short*)alloc(128ull * 512 * 2);
    unsigned short* Wd1 = (unsigned short*)alloc(128ull * 256 * 2);
    unsigned short* Ws1 = (unsigned short*)alloc(128ull * 256 * 2);
    float* bg0 = (float*)alloc(128 * 4);
    float* bd0 = (float*)alloc(128 * 4);
    float* bs0 = (float*)alloc(128 * 4);
    float* bg1 = (float*)alloc(128 * 4);
    float* bd1 = (float*)alloc(128 * 4);
    float* bs1 = (float*)alloc(128 * 4);
    int* gCnt = (int*)alloc((size_t)NBKT2 * GCNT_STRIDE * 4);
    unsigned int* bktBuf = (unsigned int*)alloc((size_t)NBKT2 * BCAP2 * 4);

    // ---- zero bucket counters, bin (+cast+build_w), place into esF ----
    k_zero<<<(NBKT2 * GCNT_STRIDE + 255) / 256, 256, 0, stream>>>(
        gCnt, NBKT2 * GCNT_STRIDE);
    k_binA<<<NB_MERGED, 256, 0, stream>>>(srcs, dsts, gCnt, bktBuf,
                                          emb_drug, emb_dis, emb_gene, xb,
                                          Wl, Wr, bl,
                                          Wg0, Wd0, Ws0, bg0, bd0, bs0,
                                          Wg1, Wd1, Ws1, bg1, bd1, bs1);
    k_placeB<<<NBKT2, 256, 0, stream>>>(gCnt, bktBuf, cnt, esF);

    const long long MOFF1 = 50000ll * 128, MOFF2 = 70000ll * 128;
    const long long MOFF3 = 80000ll * 128, MOFF4 = 130000ll * 128;

    // ---- layer 1 ----
    P5 xs1 = {{xb_drug, xb_gene, xb_gene, xb_dis, xb_gene}};
    k_agg_all<<<N_TOT / 4, 256, 0, stream>>>(xs1, cnt, esF, mean);
    Jobs jobs1 = {{
        {mean, mean + MOFF3, mean + MOFF4, xb_gene, Wg0, bg0, 1.0f / 3.0f, x1_gene, 50000, 3},
        {mean + MOFF1, nullptr, nullptr, xb_drug, Wd0, bd0, 1.0f, x1_drug, 20000, 1},
        {mean + MOFF2, nullptr, nullptr, xb_dis, Ws0, bs0, 1.0f, x1_dis, 10000, 1},
    }};
    k_gemm3<true><<<1252, 256, 0, stream>>>(jobs1);

    // ---- layer 2 ----
    P5 xs2 = {{x1_drug, x1_gene, x1_gene, x1_dis, x1_gene}};
    k_agg_all<<<N_TOT / 4, 256, 0, stream>>>(xs2, cnt, esF, mean);
    float* outp = (float*)d_out;
    Jobs jobs2 = {{
        {mean, mean + MOFF3, mean + MOFF4, x1_gene, Wg1, bg1, 1.0f / 3.0f,
         outp + 30000ull * 128, 50000, 3},
        {mean + MOFF1, nullptr, nullptr, x1_drug, Wd1, bd1, 1.0f, outp, 20000, 1},
        {mean + MOFF2, nullptr, nullptr, x1_dis, Ws1, bs1, 1.0f,
         outp + 20000ull * 128, 10000, 1},
    }};
    k_gemm3<false><<<1252, 256, 0, stream>>>(jobs2);
}

// Round 16
// 416.428 us; speedup vs baseline: 1.1617x; 1.0051x over previous
//
#include <hip/hip_runtime.h>

typedef float floatx4 __attribute__((ext_vector_type(4)));
typedef short shortx8 __attribute__((ext_vector_type(8)));

struct P5 { const void* p[5]; };

__device__ __forceinline__ float bf16_to_f(unsigned short u) {
    union { unsigned int i; float f; } v;
    v.i = ((unsigned int)u) << 16;
    return v.f;
}
__device__ __forceinline__ unsigned short f_to_bf16(float f) {
    union { float f; unsigned int i; } v;
    v.f = f;
    unsigned int lsb = (v.i >> 16) & 1u;
    unsigned int r = v.i + 0x7fffu + lsb;
    return (unsigned short)(r >> 16);
}

#define E_TOT 2720000
#define N_TOT 180000
#define CAP 96        // max degree bound: worst-type mean 32, P(deg>=96) ~ 1e-20

// two-pass build: k_binA bins edges into 704 buckets of 256 slots (w>>8) with
// per-block LDS histograms + ONE global atomic per (block,bucket) reservation.
// v3 (R13-verified): LDS record stash + EPB 2048 -> 1329 bin blocks; binA
// dropped out of top-5 (<95us, was 104 at EPB 8192 / 21.6% occupancy).
#define EPB 2048           // edges per k_binA block
#define NBA 1329           // ceil(E_TOT / EPB)
#define NBKT2 704          // ceil(N_TOT / 256)
#define BCAP2 9216         // worst bucket (drug region): mean 8192, sigma ~90 -> +11 sigma
#define GCNT_STRIDE 16     // one counter per 64B line
#define NB_MERGED (NBA + 11024)  // 1329 bin + 10000 cast + 512 bw0 + 512 bw1

// ---------------- zero (bucket counters) ----------------
__global__ __launch_bounds__(256) void k_zero(int* __restrict__ p, int n) {
    int i = blockIdx.x * 256 + threadIdx.x;
    if (i < n) p[i] = 0;
}

// ---------------- build_w body (fp32 in, bf16 out) ----------------
// Wt layouts (bf16, [128 n x K k] row-major):
//  gene K=512: [Wl(e0)|Wl(e3)|Wl(e4)|Wr(e0)+Wr(e3)+Wr(e4)]
//  drug K=256: [Wl(e1)|Wr(e1)]   dis K=256: [Wl(e2)|Wr(e2)]
__device__ void build_w_body(const float* Wl, const float* Wr, const float* bl,
                             int l, int t,
                             unsigned short* Wg, unsigned short* Wd,
                             unsigned short* Ws, float* bg, float* bd, float* bs) {
    if (t < 128 * 512) {
        int n = t >> 9;
        int kg = t & 511;
        int b = kg >> 7, k = kg & 127;
        float v;
        if (b == 0)
            v = Wl[(((size_t)l * 5 + 0) * 128 + n) * 128 + k];
        else if (b == 1)
            v = Wl[(((size_t)l * 5 + 3) * 128 + n) * 128 + k];
        else if (b == 2)
            v = Wl[(((size_t)l * 5 + 4) * 128 + n) * 128 + k];
        else
            v = Wr[(((size_t)l * 5 + 0) * 128 + n) * 128 + k] +
                Wr[(((size_t)l * 5 + 3) * 128 + n) * 128 + k] +
                Wr[(((size_t)l * 5 + 4) * 128 + n) * 128 + k];
        Wg[n * 512 + kg] = f_to_bf16(v);
    } else if (t < 131072) {
        int t2 = t - 65536;
        int which = (t2 >= 32768) ? 1 : 0;  // 0=drug(e1), 1=disease(e2)
        int t3 = which ? t2 - 32768 : t2;
        int n = t3 >> 8;
        int kg = t3 & 255;
        int b = kg >> 7, k = kg & 127;
        int ei = which ? 2 : 1;
        float v = (b == 0) ? Wl[(((size_t)l * 5 + ei) * 128 + n) * 128 + k]
                           : Wr[(((size_t)l * 5 + ei) * 128 + n) * 128 + k];
        (which ? Ws : Wd)[n * 256 + kg] = f_to_bf16(v);
    }
    if (t < 128) {
        int n = t;
        bg[n] = bl[((size_t)l * 5 + 0) * 128 + n] +
                bl[((size_t)l * 5 + 3) * 128 + n] +
                bl[((size_t)l * 5 + 4) * 128 + n];
        bd[n] = bl[((size_t)l * 5 + 1) * 128 + n];
        bs[n] = bl[((size_t)l * 5 + 2) * 128 + n];
    }
}

// ---------------- pass A: LDS-histogram binning + block reservation ----------
// blocks [0,NBA): bin 2048 edges each; [NBA,NBA+10000): cast; then 2x512 build_w.
__global__ __launch_bounds__(256) void k_binA(P5 src, P5 dst,
                                              int* __restrict__ gCnt,
                                              unsigned int* __restrict__ bktBuf,
                                              const float* __restrict__ drug,
                                              const float* __restrict__ dis,
                                              const float* __restrict__ gene,
                                              unsigned short* __restrict__ xb,
                                              const float* __restrict__ Wl,
                                              const float* __restrict__ Wr,
                                              const float* __restrict__ bl,
                                              unsigned short* __restrict__ Wg0,
                                              unsigned short* __restrict__ Wd0,
                                              unsigned short* __restrict__ Ws0,
                                              float* __restrict__ bg0,
                                              float* __restrict__ bd0,
                                              float* __restrict__ bs0,
                                              unsigned short* __restrict__ Wg1,
                                              unsigned short* __restrict__ Wd1,
                                              unsigned short* __restrict__ Ws1,
                                              float* __restrict__ bg1,
                                              float* __restrict__ bd1,
                                              float* __restrict__ bs1) {
    __shared__ unsigned int recs[EPB];      // 8 KB
    __shared__ unsigned short bkts[EPB];    // 4 KB
    __shared__ int hist[NBKT2];             // 2.75 KB
    __shared__ int gbase[NBKT2];
    __shared__ int cursor[NBKT2];
    const int b = blockIdx.x;
    const int tid = threadIdx.x;
    if (b < NBA) {
        for (int t = tid; t < NBKT2; t += 256) hist[t] = 0;
        __syncthreads();
        const int ebase[5] = {0, 640000, 1280000, 1600000, 1920000};
        const int noff[5]  = {0, 50000, 70000, 80000, 130000};
        // phase 1: read edges once, stash records + bucket ids, LDS histogram
        for (int r = 0; r < 8; ++r) {
            int il = r * 256 + tid;
            int g = b * EPB + il;
            if (g < E_TOT) {
                int t = (g < 640000) ? 0 : (g < 1280000) ? 1 : (g < 1600000) ? 2
                        : (g < 1920000) ? 3 : 4;
                int e = g - ebase[t];
                int s = ((const int*)src.p[t])[e];
                int d = ((const int*)dst.p[t])[e];
                int w = noff[t] + d;
                int bk = w >> 8;
                recs[il] = ((unsigned int)(w & 255) << 16) | (unsigned int)s;  // src < 65536
                bkts[il] = (unsigned short)bk;
                atomicAdd(&hist[bk], 1);
            }
        }
        __syncthreads();
        // one global atomic per nonempty bucket reserves a contiguous range
        for (int t = tid; t < NBKT2; t += 256) {
            int h = hist[t];
            gbase[t] = h ? atomicAdd(&gCnt[t * GCNT_STRIDE], h) : 0;
            cursor[t] = 0;
        }
        __syncthreads();
        // phase 2: write records from LDS into reserved ranges
        for (int r = 0; r < 8; ++r) {
            int il = r * 256 + tid;
            int g = b * EPB + il;
            if (g < E_TOT) {
                unsigned int rec = recs[il];
                int bk = bkts[il];
                int rank = atomicAdd(&cursor[bk], 1);
                int idx = gbase[bk] + rank;
                if (idx < BCAP2)
                    bktBuf[(size_t)bk * BCAP2 + idx] = rec;
            }
        }
        return;
    }
    int pb = b - NBA;
    if (pb < 10000) {
        int i = (pb * 256 + threadIdx.x) * 4;
        if (i >= 10240000) return;
        const float* sp;
        int off;
        if (i < 2560000) { sp = drug; off = i; }
        else if (i < 3840000) { sp = dis; off = i - 2560000; }
        else { sp = gene; off = i - 3840000; }
        floatx4 v = *(const floatx4*)(sp + off);
        ushort4 r;
        r.x = f_to_bf16(v[0]);
        r.y = f_to_bf16(v[1]);
        r.z = f_to_bf16(v[2]);
        r.w = f_to_bf16(v[3]);
        *(ushort4*)(xb + i) = r;
    } else if (pb < 10512) {
        build_w_body(Wl, Wr, bl, 0, (pb - 10000) * 256 + threadIdx.x,
                     Wg0, Wd0, Ws0, bg0, bd0, bs0);
    } else {
        build_w_body(Wl, Wr, bl, 1, (pb - 10512) * 256 + threadIdx.x,
                     Wg1, Wd1, Ws1, bg1, bd1, bs1);
    }
}

// ---------------- pass B: LDS-staged placement, coalesced esF write ----------
// One block per bucket of 256 consecutive slots. Reads the bucket's records,
// places into an LDS image of esF[256][CAP] via LDS cursors, then copies the
// whole region to global coalesced. cnt[w] = final cursors.
__global__ __launch_bounds__(256) void k_placeB(const int* __restrict__ gCnt,
                                                const unsigned int* __restrict__ bktBuf,
                                                int* __restrict__ cnt,
                                                unsigned short* __restrict__ esF) {
    __shared__ __align__(16) unsigned short sE[256 * CAP];  // 48 KB
    __shared__ int scnt[256];
    const int b = blockIdx.x;
    const int tid = threadIdx.x;
    scnt[tid] = 0;
    __syncthreads();
    int n = gCnt[b * GCNT_STRIDE];
    if (n > BCAP2) n = BCAP2;
    const unsigned int* bp = bktBuf + (size_t)b * BCAP2;
    for (int i = tid; i < n; i += 256) {
        unsigned int rec = bp[i];
        int local = rec >> 16;
        int pos = atomicAdd(&scnt[local], 1);
        if (pos < CAP)
            sE[local * CAP + pos] = (unsigned short)(rec & 0xffffu);
    }
    __syncthreads();
    int w0 = b * 256;
    int nslot = N_TOT - w0;
    if (nslot > 256) nslot = 256;
    // copy out: CAP*2 = 192 B/slot = 12 uint4 per slot
    int nvec = nslot * 12;
    const uint4* s4 = (const uint4*)sE;
    uint4* g4 = (uint4*)(esF + (size_t)w0 * CAP);
    for (int i = tid; i < nvec; i += 256) g4[i] = s4[i];
    if (tid < nslot) cnt[w0 + tid] = scnt[tid];
}

// ---------------- fused aggregate over all 180000 (type,dst) slots -----------
// One wave per slot w; 4 lane-groups of 16 handle neighbors j..j+3; each lane
// covers 8 columns (16B loads); combine via shfl_xor(16,32); 16-lane store.
// v4: explicit 2-deep software pipeline. R13/R14 both showed VGPR stuck at 24
// -> compiler kept a 1-deep load pipeline despite unroll pragmas (each ~300cyc
// gather serialized against its accumulate). Named p (accumulating) / q (load
// in flight) + index read one further stage ahead force depth-2 dataflow.
__global__ __launch_bounds__(256) void k_agg_all(P5 xs,
                                                 const int* __restrict__ cnt,
                                                 const unsigned short* __restrict__ esF,
                                                 unsigned short* __restrict__ mean) {
    __shared__ __align__(16) unsigned short nb[4][CAP];  // 768 B
    const int wslot = threadIdx.x >> 6;
    int w = blockIdx.x * 4 + wslot;
    const int lane = threadIdx.x & 63;
    const int grp = lane >> 4;        // neighbor sub-index 0..3
    const int sub = lane & 15;        // 16 lanes cover one 256B row
    const int c0 = sub << 3;          // 8 cols per lane
    int t = (w < 50000) ? 0 : (w < 70000) ? 1 : (w < 80000) ? 2 : (w < 130000) ? 3 : 4;
    int n = cnt[w];
    if (n > CAP) n = CAP;
    if (n < 0) n = 0;
    const unsigned short* ep = esF + (size_t)w * CAP;
    // preload neighbor list into LDS: 12 lanes x 8 ushorts = 96 entries
    if (lane < 12)
        *(shortx8*)(&nb[wslot][lane << 3]) = *(const shortx8*)(ep + (lane << 3));
    __syncthreads();
    const unsigned short* xp = (const unsigned short*)xs.p[t] + c0;
    const unsigned short* nbp = nb[wslot];
    float s0 = 0.f, s1 = 0.f, s2 = 0.f, s3 = 0.f;
    float s4 = 0.f, s5 = 0.f, s6 = 0.f, s7 = 0.f;
    auto accum = [&](const uint4& p) {
        s0 += bf16_to_f((unsigned short)(p.x & 0xffffu));
        s1 += bf16_to_f((unsigned short)(p.x >> 16));
        s2 += bf16_to_f((unsigned short)(p.y & 0xffffu));
        s3 += bf16_to_f((unsigned short)(p.y >> 16));
        s4 += bf16_to_f((unsigned short)(p.z & 0xffffu));
        s5 += bf16_to_f((unsigned short)(p.z >> 16));
        s6 += bf16_to_f((unsigned short)(p.w & 0xffffu));
        s7 += bf16_to_f((unsigned short)(p.w >> 16));
    };
    int j = 0;
    if (n >= 8) {
        int ia = nbp[grp];
        int ib = nbp[4 + grp];
        uint4 p = *(const uint4*)(xp + ((size_t)ia << 7));
        for (j = 8; j + 4 <= n; j += 4) {
            uint4 q = *(const uint4*)(xp + ((size_t)ib << 7));  // batch j-4 in flight
            ib = nbp[j + grp];                                   // index for batch j
            accum(p);
            p = q;
        }
        uint4 q = *(const uint4*)(xp + ((size_t)ib << 7));
        accum(p);
        accum(q);
        // processed batches 0..j-4 inclusive -> indices 0..j-1
    } else if (n >= 4) {
        int ia = nbp[grp];
        uint4 p = *(const uint4*)(xp + ((size_t)ia << 7));
        accum(p);
        j = 4;
    }
    int rem = n - j;
    if (grp < rem) {
        int sA = nbp[j + grp];
        uint4 p = *(const uint4*)(xp + ((size_t)sA << 7));
        accum(p);
    }
    s0 += __shfl_xor(s0, 16); s1 += __shfl_xor(s1, 16);
    s2 += __shfl_xor(s2, 16); s3 += __shfl_xor(s3, 16);
    s4 += __shfl_xor(s4, 16); s5 += __shfl_xor(s5, 16);
    s6 += __shfl_xor(s6, 16); s7 += __shfl_xor(s7, 16);
    s0 += __shfl_xor(s0, 32); s1 += __shfl_xor(s1, 32);
    s2 += __shfl_xor(s2, 32); s3 += __shfl_xor(s3, 32);
    s4 += __shfl_xor(s4, 32); s5 += __shfl_xor(s5, 32);
    s6 += __shfl_xor(s6, 32); s7 += __shfl_xor(s7, 32);
    if (lane < 16) {
        float ic = 1.0f / (float)((n > 1) ? n : 1);
        uint4 o;
        o.x = (unsigned int)f_to_bf16(s0 * ic) | ((unsigned int)f_to_bf16(s1 * ic) << 16);
        o.y = (unsigned int)f_to_bf16(s2 * ic) | ((unsigned int)f_to_bf16(s3 * ic) << 16);
        o.z = (unsigned int)f_to_bf16(s4 * ic) | ((unsigned int)f_to_bf16(s5 * ic) << 16);
        o.w = (unsigned int)f_to_bf16(s6 * ic) | ((unsigned int)f_to_bf16(s7 * ic) << 16);
        *(uint4*)(mean + ((size_t)w << 7) + c0) = o;
    }
}

// ---------------- merged fused GEMM (3 jobs per layer) ----------------
// out[M,128] = relu( ( [m0|m1|m2|x] @ Wt^T + bias ) * invk )
// blocks [0,782) gene, [782,1095) drug, [1095,1252) dis.
// v2: weight chunk for each K-step (one s = 128 cols) is LDS-staged
// cooperatively (coalesced 16B global loads), MFMA B-frags come from
// ds_read_b128. Row pad 136 ushorts (272B) -> conflict-free (m136).
struct GemmJob {
    const unsigned short *m0, *m1, *m2, *x, *Wt;
    const float* bias;
    float invk;
    void* out;
    int M, nacc;
};
struct Jobs { GemmJob j[3]; };

#define BPAD 136

template <bool OUTBF>
__global__ __launch_bounds__(256) void k_gemm3(Jobs jobs) {
    __shared__ __align__(16) unsigned short sB[128 * BPAD];  // 34.8 KB
    const int b = blockIdx.x;
    int ji, bloc;
    if (b < 782) { ji = 0; bloc = b; }
    else if (b < 1095) { ji = 1; bloc = b - 782; }
    else { ji = 2; bloc = b - 1095; }
    const GemmJob& J = jobs.j[ji];
    const int K = (J.nacc + 1) << 7;
    const int tid = threadIdx.x;
    const int lane = tid & 63;
    const int wave = tid >> 6;
    const int quad = lane >> 4;
    const int l16 = lane & 15;
    const int m_base = bloc * 64 + wave * 16;
    int row = m_base + l16;
    if (row > J.M - 1) row = J.M - 1;

    // staging coords: thread t covers row t>>1, half t&1 (64 ushorts = 8x16B)
    const int srow = tid >> 1;
    const int shalf = tid & 1;
    unsigned short* sdst = sB + srow * BPAD + shalf * 64;

    floatx4 acc[8];
#pragma unroll
    for (int i = 0; i < 8; i++) acc[i] = floatx4{0.f, 0.f, 0.f, 0.f};

    for (int s = 0; s <= J.nacc; s++) {
        // ---- stage Wt[:, s*128 .. s*128+128) into LDS (32 KB, coalesced) ----
        {
            const unsigned short* wsrc =
                J.Wt + (size_t)srow * K + (s << 7) + shalf * 64;
#pragma unroll
            for (int i = 0; i < 8; i++) {
                *(shortx8*)(sdst + i * 8) = *(const shortx8*)(wsrc + i * 8);
            }
        }
        __syncthreads();
        const unsigned short* mp =
            ((s == J.nacc) ? J.x : (s == 0) ? J.m0 : (s == 1) ? J.m1 : J.m2) +
            ((size_t)row << 7);
#pragma unroll
        for (int kq = 0; kq < 4; kq++) {
            const int ko = (kq << 5) + (quad << 3);
            shortx8 afrag = *(const shortx8*)(mp + ko);
#pragma unroll
            for (int nt = 0; nt < 8; nt++) {
                shortx8 bfrag =
                    *(const shortx8*)(sB + ((nt << 4) + l16) * BPAD + ko);
                acc[nt] = __builtin_amdgcn_mfma_f32_16x16x32_bf16(afrag, bfrag, acc[nt], 0, 0, 0);
            }
        }
        __syncthreads();
    }

    // epilogue: D mapping col=lane&15, row=quad*4+reg
#pragma unroll
    for (int nt = 0; nt < 8; nt++) {
        const int col = (nt << 4) + l16;
        const float bv = J.bias[col];
#pragma unroll
        for (int r = 0; r < 4; r++) {
            const int orow = m_base + (quad << 2) + r;
            if (orow < J.M) {
                float v = fmaxf((acc[nt][r] + bv) * J.invk, 0.f);
                if (OUTBF)
                    ((unsigned short*)J.out)[((size_t)orow << 7) + col] = f_to_bf16(v);
                else
                    ((float*)J.out)[((size_t)orow << 7) + col] = v;
            }
        }
    }
}

extern "C" void kernel_launch(void* const* d_in, const int* in_sizes, int n_in,
                              void* d_out, int out_size, void* d_ws, size_t ws_size,
                              hipStream_t stream) {
    const float* emb_drug = (const float*)d_in[0];
    const float* emb_dis  = (const float*)d_in[1];
    const float* emb_gene = (const float*)d_in[2];
    const float* Wl = (const float*)d_in[3];
    const float* Wr = (const float*)d_in[4];
    const float* bl = (const float*)d_in[5];
    P5 srcs = {{d_in[6], d_in[8], d_in[10], d_in[12], d_in[14]}};
    P5 dsts = {{d_in[7], d_in[9], d_in[11], d_in[13], d_in[15]}};

    char* base = (char*)d_ws;
    size_t off = 0;
    auto alloc = [&](size_t bytes) -> void* {
        void* r = base + off;
        off = (off + bytes + 255) & ~(size_t)255;
        return r;
    };
    int* cnt = (int*)alloc((size_t)N_TOT * 4);
    unsigned short* esF = (unsigned short*)alloc((size_t)N_TOT * CAP * 2);
    unsigned short* mean = (unsigned short*)alloc(180000ull * 128 * 2);
    unsigned short* xb = (unsigned short*)alloc(80000ull * 128 * 2);
    unsigned short* xb_drug = xb;
    unsigned short* xb_dis  = xb + 20000ull * 128;
    unsigned short* xb_gene = xb + 30000ull * 128;
    unsigned short* x1_drug = (unsigned short*)alloc(20000ull * 128 * 2);
    unsigned short* x1_dis  = (unsigned short*)alloc(10000ull * 128 * 2);
    unsigned short* x1_gene = (unsigned short*)alloc(50000ull * 128 * 2);
    unsigned short* Wg0 = (unsigned short*)alloc(128ull * 512 * 2);
    unsigned short* Wd0 = (unsigned short*)alloc(128ull * 256 * 2);
    unsigned short* Ws0 = (unsigned short*)alloc(128ull * 256 * 2);
    unsigned short* Wg1 = (unsigned short*)alloc(128ull * 512 * 2);
    unsigned short* Wd1 = (unsigned short*)alloc(128ull * 256 * 2);
    unsigned short* Ws1 = (unsigned short*)alloc(128ull * 256 * 2);
    float* bg0 = (float*)alloc(128 * 4);
    float* bd0 = (float*)alloc(128 * 4);
    float* bs0 = (float*)alloc(128 * 4);
    float* bg1 = (float*)alloc(128 * 4);
    float* bd1 = (float*)alloc(128 * 4);
    float* bs1 = (float*)alloc(128 * 4);
    int* gCnt = (int*)alloc((size_t)NBKT2 * GCNT_STRIDE * 4);
    unsigned int* bktBuf = (unsigned int*)alloc((size_t)NBKT2 * BCAP2 * 4);

    // ---- zero bucket counters, bin (+cast+build_w), place into esF ----
    k_zero<<<(NBKT2 * GCNT_STRIDE + 255) / 256, 256, 0, stream>>>(
        gCnt, NBKT2 * GCNT_STRIDE);
    k_binA<<<NB_MERGED, 256, 0, stream>>>(srcs, dsts, gCnt, bktBuf,
                                          emb_drug, emb_dis, emb_gene, xb,
                                          Wl, Wr, bl,
                                          Wg0, Wd0, Ws0, bg0, bd0, bs0,
                                          Wg1, Wd1, Ws1, bg1, bd1, bs1);
    k_placeB<<<NBKT2, 256, 0, stream>>>(gCnt, bktBuf, cnt, esF);

    const long long MOFF1 = 50000ll * 128, MOFF2 = 70000ll * 128;
    const long long MOFF3 = 80000ll * 128, MOFF4 = 130000ll * 128;

    // ---- layer 1 ----
    P5 xs1 = {{xb_drug, xb_gene, xb_gene, xb_dis, xb_gene}};
    k_agg_all<<<N_TOT / 4, 256, 0, stream>>>(xs1, cnt, esF, mean);
    Jobs jobs1 = {{
        {mean, mean + MOFF3, mean + MOFF4, xb_gene, Wg0, bg0, 1.0f / 3.0f, x1_gene, 50000, 3},
        {mean + MOFF1, nullptr, nullptr, xb_drug, Wd0, bd0, 1.0f, x1_drug, 20000, 1},
        {mean + MOFF2, nullptr, nullptr, xb_dis, Ws0, bs0, 1.0f, x1_dis, 10000, 1},
    }};
    k_gemm3<true><<<1252, 256, 0, stream>>>(jobs1);

    // ---- layer 2 ----
    P5 xs2 = {{x1_drug, x1_gene, x1_gene, x1_dis, x1_gene}};
    k_agg_all<<<N_TOT / 4, 256, 0, stream>>>(xs2, cnt, esF, mean);
    float* outp = (float*)d_out;
    Jobs jobs2 = {{
        {mean, mean + MOFF3, mean + MOFF4, x1_gene, Wg1, bg1, 1.0f / 3.0f,
         outp + 30000ull * 128, 50000, 3},
        {mean + MOFF1, nullptr, nullptr, x1_drug, Wd1, bd1, 1.0f, outp, 20000, 1},
        {mean + MOFF2, nullptr, nullptr, x1_dis, Ws1, bs1, 1.0f,
         outp + 20000ull * 128, 10000, 1},
    }};
    k_gemm3<false><<<1252, 256, 0, stream>>>(jobs2);
}